// Round 8
// baseline (236.346 us; speedup 1.0000x reference)
//
#include <hip/hip_runtime.h>

#define BB 16
#define PP 96
#define TT 128
#define VV 64
#define NN 16
#define DD 128
#define BPP (BB * PP)     // 1536 attention blocks
#define NPASS (BB * 32)   // 512 passthrough blocks
#define SB 136            // bf16 row stride for KM tile (272 B)
#define ST 72             // KCT / A row stride (144 B)
#define SSF 68            // S f32 row stride (272 B = same bytes as SB)
#define SCALE 0.08838834764831845f
#define SLICE 4352        // per-wave byte slice in region1 (= 16 rows * 272 B)

typedef __bf16 bf16x8 __attribute__((ext_vector_type(8)));
typedef __bf16 bf16x4 __attribute__((ext_vector_type(4)));
typedef float  floatx4 __attribute__((ext_vector_type(4)));
typedef unsigned int uint32x4 __attribute__((ext_vector_type(4)));

#define MFMA16(a, b, c) __builtin_amdgcn_mfma_f32_16x16x32_bf16(a, b, c, 0, 0, 0)

__device__ __forceinline__ bf16x8 cvt8(float4 a, float4 b) {
    return bf16x8{(__bf16)a.x, (__bf16)a.y, (__bf16)a.z, (__bf16)a.w,
                  (__bf16)b.x, (__bf16)b.y, (__bf16)b.z, (__bf16)b.w};
}

// A-frags for a 16-row strip directly from global f32 (row stride DD).
__device__ __forceinline__ void loadA_g(const float* Xs, int lm, int lq, bf16x8 af[4]) {
    const float4* p = (const float4*)(Xs + lm * DD + lq * 8);
#pragma unroll
    for (int ks = 0; ks < 4; ++ks) af[ks] = cvt8(p[8 * ks], p[8 * ks + 1]);
}

// A-frags from LDS bf16 (row stride sa), kblocks k-chunks of 32
__device__ __forceinline__ void loadA_l(const __bf16* As, int sa, int lm, int lq,
                                        bf16x8* af, int kblocks) {
#pragma unroll
    for (int ks = 0; ks < 4; ++ks) {
        if (ks >= kblocks) break;
        af[ks] = *(const bf16x8*)(As + lm * sa + lq * 8 + 32 * ks);
    }
}

// acc[nb] = A_strip @ B^T ; B row-major bf16 stride sb (global weights or LDS).
// ks-major with an explicit 8-fragment load burst per ks-slice: all B loads
// for the slice are issued back-to-back (one latency amortized 8x), then 8
// INDEPENDENT MFMAs consume them. The old nb-major form issued
// load->mfma->load->mfma serially and ran at ~1 L2 latency per step -- that
// exposed ~68 weight-load latencies per wave and dominated block time.
__device__ __forceinline__ void mmB(const bf16x8* af, const __bf16* B, int sb,
                                    int lm, int lq, floatx4* acc, int nblocks, int kblocks) {
#pragma unroll
    for (int nb = 0; nb < 8; ++nb) {
        if (nb >= nblocks) break;
        acc[nb] = floatx4{0.f, 0.f, 0.f, 0.f};
    }
#pragma unroll
    for (int ks = 0; ks < 4; ++ks) {
        if (ks >= kblocks) break;
        bf16x8 bfr[8];
#pragma unroll
        for (int nb = 0; nb < 8; ++nb) {
            if (nb >= nblocks) break;
            bfr[nb] = *(const bf16x8*)(B + (nb * 16 + lm) * sb + lq * 8 + 32 * ks);
        }
#pragma unroll
        for (int nb = 0; nb < 8; ++nb) {
            if (nb >= nblocks) break;
            acc[nb] = MFMA16(af[ks], bfr[nb], acc[nb]);
        }
    }
}

// ---------------------------------------------------------------------------
// prep: Wb = bf16{ M2 = Wq^T@Wkv (row i, col j = sum_k Wq[k][i] Wkv[k][j])
//               | Wcomb = Wout@Wkv
//               | Bq: 16 rows, each = bqk = bq@Wkv }
//       bcomb = Wout@bkv + bout
// Score path: S = Q @ (K@M2^T)^T + (bqk.k_n per-key bias); row-constant
// terms are softmax-invariant and dropped. Output: Y = A@(K@Wcomb^T)+bcomb.
// 4-way split accumulators (no fast-math -> manual reassociation).
// ---------------------------------------------------------------------------
__global__ void prep(const float* __restrict__ Wq, const float* __restrict__ Wkv,
                     const float* __restrict__ Wout, const float* __restrict__ bq,
                     const float* __restrict__ bkv, const float* __restrict__ bout,
                     __bf16* __restrict__ Wb, float* __restrict__ bcomb) {
    int i = blockIdx.x, j = threadIdx.x;
    float m2[4] = {0.f, 0.f, 0.f, 0.f}, wc[4] = {0.f, 0.f, 0.f, 0.f};
    for (int k = 0; k < DD; k += 4) {
#pragma unroll
        for (int u = 0; u < 4; ++u) {
            m2[u] += Wq[(k + u) * DD + i] * Wkv[(k + u) * DD + j];   // M2[i][j]
            wc[u] += Wout[i * DD + k + u] * Wkv[(k + u) * DD + j];   // Wcomb[i][j]
        }
    }
    Wb[i * DD + j]         = (__bf16)((m2[0] + m2[1]) + (m2[2] + m2[3]));
    Wb[16384 + i * DD + j] = (__bf16)((wc[0] + wc[1]) + (wc[2] + wc[3]));
    if (i < 16) {  // Bq tile: 16 identical rows = bqk
        float bk[4] = {0.f, 0.f, 0.f, 0.f};
        for (int k = 0; k < DD; k += 4) {
#pragma unroll
            for (int u = 0; u < 4; ++u) bk[u] += bq[k + u] * Wkv[(k + u) * DD + j];
        }
        Wb[32768 + i * DD + j] = (__bf16)((bk[0] + bk[1]) + (bk[2] + bk[3]));
    }
    if (i == 0) {
        float bs[4] = {bout[j], 0.f, 0.f, 0.f};
        for (int k = 0; k < DD; k += 4) {
#pragma unroll
            for (int u = 0; u < 4; ++u) bs[u] += Wout[j * DD + k + u] * bkv[k + u];
        }
        bcomb[j] = (bs[0] + bs[1]) + (bs[2] + bs[3]);
    }
}

// ---------------------------------------------------------------------------
// fused: blocks [0,1536) = attention per (b,p); [1536,2048) = passthrough.
// 4 waves; wave w owns rows [16w,16w+16). ONE barrier per block.
// Pre-barrier:  K loads -> KC=K@Wcomb^T -> KCT scatter; KM=K@M2^T -> smKM
//               (row-major); sbias = K.bqk via 1 MFMA vs broadcast-Bq tile;
//               Q loads issued (held in regs across the barrier).
// Post-barrier: S = Q@KM^T directly from qr regs -> softmax(+sbias)/
//               dup-scatter -> Y = A@KC + bcomb -> HBM.
// ---------------------------------------------------------------------------
__global__ __launch_bounds__(256, 3) void fused(
    const float* __restrict__ queries, const float* __restrict__ keys,
    const int* __restrict__ ccc, const __bf16* __restrict__ Wb,
    const float* __restrict__ bcomb, float* __restrict__ out) {
    __shared__ __align__(16) char lds[53504];
    __bf16* R1    = (__bf16*)lds;             // 17408: S(f32) / A (per-wave slices)
    __bf16* smKM  = (__bf16*)(lds + 17408);   // 17408: KM = K@M2^T, row-major 64 x 128
    __bf16* smKCT = (__bf16*)(lds + 34816);   // 18432: (K@Wcomb^T)^T, 128 x 64
    float*  smSB  = (float*)(lds + 53248);    // 256: sbias[64] = K.bqk per key
    float*  smS   = (float*)lds;

    int bl = blockIdx.x, t = threadIdx.x;
    int w = t >> 6, L = t & 63, lm = L & 15, lq = L >> 4;

    bf16x8 af[4];
    floatx4 acc[8];

    if (bl >= BPP) {
        // ---- passthrough: out[b, wi rows] = keys @ Wcomb^T + bcomb ----
        int pb = bl - BPP;
        int b = pb >> 5, wi = pb & 31;
        const float* Xs = keys + ((long)b * TT * VV + wi * 64 + w * 16) * DD;
        float* Yg = out + ((long)b * TT * VV + wi * 64) * DD;
        loadA_g(Xs, lm, lq, af);
        mmB(af, Wb + 16384, DD, lm, lq, acc, 8, 4);
#pragma unroll
        for (int nb = 0; nb < 8; ++nb) {
            float bv = bcomb[nb * 16 + lm];
#pragma unroll
            for (int r = 0; r < 4; ++r)
                Yg[(long)(w * 16 + lq * 4 + r) * DD + nb * 16 + lm] = acc[nb][r] + bv;
        }
        return;
    }

    int b = bl / PP, p = bl % PP;
    const float* Qg = queries + ((long)(b * PP + p) * VV) * DD;
    const float* Kg = keys + ((long)(b * TT + 32 + p) * VV) * DD;
    float* Yg = out + ((long)(b * TT + 32 + p) * VV) * DD;

    // ---- P0k: K strip loads (qr NOT live here) ----
    float4 kr[8];
    {
        const float4* kp = (const float4*)(Kg + (w * 16 + lm) * DD + lq * 8);
#pragma unroll
        for (int ks = 0; ks < 4; ++ks) {
            kr[2 * ks] = kp[8 * ks]; kr[2 * ks + 1] = kp[8 * ks + 1];
        }
    }

    // ---- KC = K @ Wcomb^T (no bias; bcomb added in the epilogue) ----
#pragma unroll
    for (int ks = 0; ks < 4; ++ks) af[ks] = cvt8(kr[2 * ks], kr[2 * ks + 1]);
    mmB(af, Wb + 16384, DD, lm, lq, acc, 8, 4);

    // ---- issue Q strip loads: held in regs across the barrier (R3-proven) ----
    float4 qr[8];
    {
        const float4* qp = (const float4*)(Qg + (w * 16 + lm) * DD + lq * 8);
#pragma unroll
        for (int ks = 0; ks < 4; ++ks) {
            qr[2 * ks] = qp[8 * ks]; qr[2 * ks + 1] = qp[8 * ks + 1];
        }
    }

    // ---- KCT transpose-scatter (C-layout -> 128 d-rows x 64 keys) ----
#pragma unroll
    for (int nb = 0; nb < 8; ++nb) {
        bf16x4 tp;
#pragma unroll
        for (int r = 0; r < 4; ++r) tp[r] = (__bf16)acc[nb][r];
        *(bf16x4*)(smKCT + (nb * 16 + lm) * ST + w * 16 + lq * 4) = tp;
    }

    // ---- KM = K @ M2^T -> smKM row-major (B-operand of the S-mfma) ----
    mmB(af, Wb, DD, lm, lq, acc, 8, 4);

    // ---- sbias = K . bqk via one MFMA against the broadcast-Bq tile ----
    floatx4 sbacc{0.f, 0.f, 0.f, 0.f};
    {
        bf16x8 bqf[4];
#pragma unroll
        for (int ks = 0; ks < 4; ++ks)
            bqf[ks] = *(const bf16x8*)(Wb + 32768 + lm * DD + lq * 8 + 32 * ks);
#pragma unroll
        for (int ks = 0; ks < 4; ++ks) sbacc = MFMA16(af[ks], bqf[ks], sbacc);
    }

#pragma unroll
    for (int nb = 0; nb < 8; ++nb)
#pragma unroll
        for (int r = 0; r < 4; ++r)
            smKM[(w * 16 + lq * 4 + r) * SB + nb * 16 + lm] = (__bf16)acc[nb][r];
    if (lm == 0) {
#pragma unroll
        for (int r = 0; r < 4; ++r) smSB[w * 16 + lq * 4 + r] = sbacc[r];
    }

    // ---- ccc row loads (L2-hot, consumed in P4) ----
    int se[NN];
    {
        const int4* cp = (const int4*)(ccc + ((long)b * VV + w * 16 + lm) * NN);
#pragma unroll
        for (int i = 0; i < 4; ++i) {
            int4 c4 = cp[i];
            se[4 * i] = c4.x; se[4 * i + 1] = c4.y;
            se[4 * i + 2] = c4.z; se[4 * i + 3] = c4.w;
        }
    }
    __syncthreads();  // B1: publish smKM/smKCT/smSB (the ONLY barrier)

    // ---- P3: S = Q @ KM^T (f32), A-frags straight from qr regs ----
#pragma unroll
    for (int ks = 0; ks < 4; ++ks) af[ks] = cvt8(qr[2 * ks], qr[2 * ks + 1]);
    mmB(af, smKM, SB, lm, lq, acc, 4, 4);
#pragma unroll
    for (int nb = 0; nb < 4; ++nb)
#pragma unroll
        for (int r = 0; r < 4; ++r)
            smS[(w * 16 + lq * 4 + r) * SSF + nb * 16 + lm] = acc[nb][r];

    // ---- P4: softmax(+sbias) + dup-total scatter, all 64 lanes, no RMW ----
    __bf16* smAsl = (__bf16*)(lds + w * SLICE);  // A strip: 16 rows x ST bf16
    {
        int g = lq;  // lane handles row lm, n-quad g
        float sg[NN];
        const float* Srow = smS + (w * 16 + lm) * SSF;
#pragma unroll
        for (int n = 0; n < NN; ++n) sg[n] = Srow[se[n]] + smSB[se[n]];  // reads first
        __builtin_amdgcn_sched_barrier(0);  // keep A-strip zeroing after S gather (regions alias)
        // zero A strip cols [0,64): lane L zeroes row L>>2, bytes (L&3)*32 .. +32
        {
            uint32x4 z{0u, 0u, 0u, 0u};
            char* zb = (char*)smAsl + (L >> 2) * (ST * 2) + (L & 3) * 32;
            *(uint32x4*)zb = z;
            *(uint32x4*)(zb + 16) = z;
        }
        float mx = -1e30f;
#pragma unroll
        for (int n = 0; n < NN; ++n) { sg[n] *= SCALE; mx = fmaxf(mx, sg[n]); }
        float sum = 0.f;
#pragma unroll
        for (int n = 0; n < NN; ++n) { sg[n] = __expf(sg[n] - mx); sum += sg[n]; }
        float inv = 1.f / sum;
#pragma unroll
        for (int j = 0; j < 4; ++j) {  // dup groups write identical totals
            int u = se[g * 4 + j];
            float tot = 0.f;
#pragma unroll
            for (int n = 0; n < NN; ++n) tot += (se[n] == u) ? sg[n] : 0.f;
            smAsl[lm * ST + u] = (__bf16)(tot * inv);
        }
    }

    // ---- P5: Y = A @ KC + bcomb (B from KCT), K=64 -> global directly ----
    loadA_l(smAsl, ST, lm, lq, af, 2);
    mmB(af, smKCT, ST, lm, lq, acc, 8, 2);
#pragma unroll
    for (int nb = 0; nb < 8; ++nb) {
        float bv = bcomb[nb * 16 + lm];
#pragma unroll
        for (int r = 0; r < 4; ++r)
            Yg[(long)(w * 16 + lq * 4 + r) * DD + nb * 16 + lm] = acc[nb][r] + bv;
    }
}

extern "C" void kernel_launch(void* const* d_in, const int* in_sizes, int n_in,
                              void* d_out, int out_size, void* d_ws, size_t ws_size,
                              hipStream_t stream) {
    const float* queries = (const float*)d_in[0];
    const float* keys    = (const float*)d_in[1];
    const int*   ccc     = (const int*)d_in[2];
    const float* Wq      = (const float*)d_in[3];
    const float* bq      = (const float*)d_in[4];
    const float* Wkv     = (const float*)d_in[5];
    const float* bkv     = (const float*)d_in[6];
    const float* Wout    = (const float*)d_in[7];
    const float* bout    = (const float*)d_in[8];
    float* out = (float*)d_out;

    __bf16* Wb    = (__bf16*)d_ws;                        // M2|Wcomb|Bq bf16 = 96 KB
    float*  bcomb = (float*)((char*)d_ws + 98304);        // 128 f32

    prep<<<dim3(128), dim3(128), 0, stream>>>(Wq, Wkv, Wout, bq, bkv, bout, Wb, bcomb);

    fused<<<dim3(BPP + NPASS), dim3(256), 0, stream>>>(
        queries, keys, ccc, Wb, bcomb, out);
}

// Round 9
// 229.086 us; speedup vs baseline: 1.0317x; 1.0317x over previous
//
#include <hip/hip_runtime.h>

#define BB 16
#define PP 96
#define TT 128
#define VV 64
#define NN 16
#define DD 128
#define BPP (BB * PP)     // 1536 attention blocks
#define NPASS (BB * 32)   // 512 passthrough blocks
#define SB 136            // bf16 row stride for KM tile (272 B)
#define ST 72             // KCT / A row stride (144 B)
#define SSF 68            // S f32 row stride (272 B = same bytes as SB)
#define SCALE 0.08838834764831845f
#define SLICE 4352        // per-wave byte slice in the S/A region (16 rows * 272 B)

typedef __bf16 bf16x8 __attribute__((ext_vector_type(8)));
typedef __bf16 bf16x4 __attribute__((ext_vector_type(4)));
typedef float  floatx4 __attribute__((ext_vector_type(4)));
typedef unsigned int uint32x4 __attribute__((ext_vector_type(4)));

#define MFMA16(a, b, c) __builtin_amdgcn_mfma_f32_16x16x32_bf16(a, b, c, 0, 0, 0)

__device__ __forceinline__ bf16x8 cvt8(float4 a, float4 b) {
    return bf16x8{(__bf16)a.x, (__bf16)a.y, (__bf16)a.z, (__bf16)a.w,
                  (__bf16)b.x, (__bf16)b.y, (__bf16)b.z, (__bf16)b.w};
}

// A-frags for a 16-row strip directly from global f32 (row stride DD).
__device__ __forceinline__ void loadA_g(const float* Xs, int lm, int lq, bf16x8 af[4]) {
    const float4* p = (const float4*)(Xs + lm * DD + lq * 8);
#pragma unroll
    for (int ks = 0; ks < 4; ++ks) af[ks] = cvt8(p[8 * ks], p[8 * ks + 1]);
}

// A-frags from LDS bf16 (row stride sa), kblocks k-chunks of 32
__device__ __forceinline__ void loadA_l(const __bf16* As, int sa, int lm, int lq,
                                        bf16x8* af, int kblocks) {
#pragma unroll
    for (int ks = 0; ks < 4; ++ks) {
        if (ks >= kblocks) break;
        af[ks] = *(const bf16x8*)(As + lm * sa + lq * 8 + 32 * ks);
    }
}

// acc[nb] = A_strip @ B^T ; B row-major bf16 stride sb (global weights or LDS).
// nb-major form (R7-proven). The ks-major 8-load burst variant (R8) forced
// scratch spills at the allocator's 84-reg target and regressed -- keep this.
__device__ __forceinline__ void mmB(const bf16x8* af, const __bf16* B, int sb,
                                    int lm, int lq, floatx4* acc, int nblocks, int kblocks) {
#pragma unroll
    for (int nb = 0; nb < 8; ++nb) {
        if (nb >= nblocks) break;
        acc[nb] = floatx4{0.f, 0.f, 0.f, 0.f};
#pragma unroll
        for (int ks = 0; ks < 4; ++ks) {
            if (ks >= kblocks) break;
            bf16x8 bf = *(const bf16x8*)(B + (nb * 16 + lm) * sb + lq * 8 + 32 * ks);
            acc[nb] = MFMA16(af[ks], bf, acc[nb]);
        }
    }
}

// ---------------------------------------------------------------------------
// prep: Wb = bf16{ M2 = Wq^T@Wkv (row i, col j = sum_k Wq[k][i] Wkv[k][j])
//               | Wcomb = Wout@Wkv
//               | Bq: 16 rows, each = bqk = bq@Wkv }
//       bcomb = Wout@bkv + bout
// Score path: S = Q @ (K@M2^T)^T + (bqk.k_n per-key bias); row-constant
// terms are softmax-invariant and dropped. Output: Y = A@(K@Wcomb^T)+bcomb.
// 4-way split accumulators (no fast-math -> manual reassociation).
// ---------------------------------------------------------------------------
__global__ void prep(const float* __restrict__ Wq, const float* __restrict__ Wkv,
                     const float* __restrict__ Wout, const float* __restrict__ bq,
                     const float* __restrict__ bkv, const float* __restrict__ bout,
                     __bf16* __restrict__ Wb, float* __restrict__ bcomb) {
    int i = blockIdx.x, j = threadIdx.x;
    float m2[4] = {0.f, 0.f, 0.f, 0.f}, wc[4] = {0.f, 0.f, 0.f, 0.f};
    for (int k = 0; k < DD; k += 4) {
#pragma unroll
        for (int u = 0; u < 4; ++u) {
            m2[u] += Wq[(k + u) * DD + i] * Wkv[(k + u) * DD + j];   // M2[i][j]
            wc[u] += Wout[i * DD + k + u] * Wkv[(k + u) * DD + j];   // Wcomb[i][j]
        }
    }
    Wb[i * DD + j]         = (__bf16)((m2[0] + m2[1]) + (m2[2] + m2[3]));
    Wb[16384 + i * DD + j] = (__bf16)((wc[0] + wc[1]) + (wc[2] + wc[3]));
    if (i < 16) {  // Bq tile: 16 identical rows = bqk
        float bk[4] = {0.f, 0.f, 0.f, 0.f};
        for (int k = 0; k < DD; k += 4) {
#pragma unroll
            for (int u = 0; u < 4; ++u) bk[u] += bq[k + u] * Wkv[(k + u) * DD + j];
        }
        Wb[32768 + i * DD + j] = (__bf16)((bk[0] + bk[1]) + (bk[2] + bk[3]));
    }
    if (i == 0) {
        float bs[4] = {bout[j], 0.f, 0.f, 0.f};
        for (int k = 0; k < DD; k += 4) {
#pragma unroll
            for (int u = 0; u < 4; ++u) bs[u] += Wout[j * DD + k + u] * bkv[k + u];
        }
        bcomb[j] = (bs[0] + bs[1]) + (bs[2] + bs[3]);
    }
}

// ---------------------------------------------------------------------------
// fused: blocks [0,1536) = attention per (b,p); [1536,2048) = passthrough.
// 4 waves; wave w owns rows [16w,16w+16). TWO barriers per block.
// LDS 36096 -> 4 blocks/CU (16 waves):
//   region SA (0..17408):     KM = K@M2^T (written pre-B1, read in P3), then
//                             after B2 reused as per-wave S(f32)/A slices.
//   region KCT (17408..35840): (K@Wcomb^T)^T, 128 x ST (pre-B1 .. P5)
//   region SB (35840..36096):  sbias[64] = K.bqk per key
// P3's S output is carried across B2 in acc registers (already live there),
// so no extra register state is held across any barrier.
// Pre-barrier:  K loads -> KC=K@Wcomb^T -> KCT scatter; KM=K@M2^T -> SA;
//               sbias via 1 MFMA vs broadcast-Bq tile; Q loads -> regs.
// Post-B1: S = Q@KM^T (reads SA). B2. S->SA slice, softmax(+sbias)/
//               dup-scatter -> A, then Y = A@KC + bcomb -> HBM.
// ---------------------------------------------------------------------------
__global__ __launch_bounds__(256, 3) void fused(
    const float* __restrict__ queries, const float* __restrict__ keys,
    const int* __restrict__ ccc, const __bf16* __restrict__ Wb,
    const float* __restrict__ bcomb, float* __restrict__ out) {
    __shared__ __align__(16) char lds[36096];
    __bf16* smKM  = (__bf16*)lds;             // pre-B2: KM row-major 64 x SB
    __bf16* smKCT = (__bf16*)(lds + 17408);   // 18432: (K@Wcomb^T)^T, 128 x ST
    float*  smSB  = (float*)(lds + 35840);    // 256: sbias[64] = K.bqk per key
    float*  smS   = (float*)lds;              // post-B2: S strips (per-wave slices)

    int bl = blockIdx.x, t = threadIdx.x;
    int w = t >> 6, L = t & 63, lm = L & 15, lq = L >> 4;

    bf16x8 af[4];
    floatx4 acc[8];

    if (bl >= BPP) {
        // ---- passthrough: out[b, wi rows] = keys @ Wcomb^T + bcomb ----
        int pb = bl - BPP;
        int b = pb >> 5, wi = pb & 31;
        const float* Xs = keys + ((long)b * TT * VV + wi * 64 + w * 16) * DD;
        float* Yg = out + ((long)b * TT * VV + wi * 64) * DD;
        loadA_g(Xs, lm, lq, af);
        mmB(af, Wb + 16384, DD, lm, lq, acc, 8, 4);
#pragma unroll
        for (int nb = 0; nb < 8; ++nb) {
            float bv = bcomb[nb * 16 + lm];
#pragma unroll
            for (int r = 0; r < 4; ++r)
                Yg[(long)(w * 16 + lq * 4 + r) * DD + nb * 16 + lm] = acc[nb][r] + bv;
        }
        return;
    }

    int b = bl / PP, p = bl % PP;
    const float* Qg = queries + ((long)(b * PP + p) * VV) * DD;
    const float* Kg = keys + ((long)(b * TT + 32 + p) * VV) * DD;
    float* Yg = out + ((long)(b * TT + 32 + p) * VV) * DD;

    // ---- P0k: K strip loads (qr NOT live here) ----
    float4 kr[8];
    {
        const float4* kp = (const float4*)(Kg + (w * 16 + lm) * DD + lq * 8);
#pragma unroll
        for (int ks = 0; ks < 4; ++ks) {
            kr[2 * ks] = kp[8 * ks]; kr[2 * ks + 1] = kp[8 * ks + 1];
        }
    }

    // ---- KC = K @ Wcomb^T (no bias; bcomb added in the epilogue) ----
#pragma unroll
    for (int ks = 0; ks < 4; ++ks) af[ks] = cvt8(kr[2 * ks], kr[2 * ks + 1]);
    mmB(af, Wb + 16384, DD, lm, lq, acc, 8, 4);

    // ---- issue Q strip loads: held in regs across the barrier (R3-proven) ----
    float4 qr[8];
    {
        const float4* qp = (const float4*)(Qg + (w * 16 + lm) * DD + lq * 8);
#pragma unroll
        for (int ks = 0; ks < 4; ++ks) {
            qr[2 * ks] = qp[8 * ks]; qr[2 * ks + 1] = qp[8 * ks + 1];
        }
    }

    // ---- KCT transpose-scatter (C-layout -> 128 d-rows x 64 keys) ----
#pragma unroll
    for (int nb = 0; nb < 8; ++nb) {
        bf16x4 tp;
#pragma unroll
        for (int r = 0; r < 4; ++r) tp[r] = (__bf16)acc[nb][r];
        *(bf16x4*)(smKCT + (nb * 16 + lm) * ST + w * 16 + lq * 4) = tp;
    }

    // ---- KM = K @ M2^T -> smKM row-major (B-operand of the S-mfma) ----
    mmB(af, Wb, DD, lm, lq, acc, 8, 4);

    // ---- sbias = K . bqk via one MFMA against the broadcast-Bq tile ----
    floatx4 sbacc{0.f, 0.f, 0.f, 0.f};
#pragma unroll
    for (int ks = 0; ks < 4; ++ks) {
        bf16x8 bf = *(const bf16x8*)(Wb + 32768 + lm * DD + lq * 8 + 32 * ks);
        sbacc = MFMA16(af[ks], bf, sbacc);
    }

#pragma unroll
    for (int nb = 0; nb < 8; ++nb)
#pragma unroll
        for (int r = 0; r < 4; ++r)
            smKM[(w * 16 + lq * 4 + r) * SB + nb * 16 + lm] = (__bf16)acc[nb][r];
    if (lm == 0) {
#pragma unroll
        for (int r = 0; r < 4; ++r) smSB[w * 16 + lq * 4 + r] = sbacc[r];
    }

    // ---- ccc row loads (L2-hot, consumed in P4) ----
    int se[NN];
    {
        const int4* cp = (const int4*)(ccc + ((long)b * VV + w * 16 + lm) * NN);
#pragma unroll
        for (int i = 0; i < 4; ++i) {
            int4 c4 = cp[i];
            se[4 * i] = c4.x; se[4 * i + 1] = c4.y;
            se[4 * i + 2] = c4.z; se[4 * i + 3] = c4.w;
        }
    }
    __syncthreads();  // B1: publish smKM/smKCT/smSB

    // ---- P3: S = Q @ KM^T (f32), A-frags straight from qr regs ----
#pragma unroll
    for (int ks = 0; ks < 4; ++ks) af[ks] = cvt8(qr[2 * ks], qr[2 * ks + 1]);
    mmB(af, smKM, SB, lm, lq, acc, 4, 4);
    __syncthreads();  // B2: all waves done reading KM -> SA region becomes S/A
#pragma unroll
    for (int nb = 0; nb < 4; ++nb)
#pragma unroll
        for (int r = 0; r < 4; ++r)
            smS[(w * 16 + lq * 4 + r) * SSF + nb * 16 + lm] = acc[nb][r];

    // ---- P4: softmax(+sbias) + dup-total scatter, all 64 lanes, no RMW ----
    __bf16* smAsl = (__bf16*)(lds + w * SLICE);  // A strip: 16 rows x ST bf16
    {
        int g = lq;  // lane handles row lm, n-quad g
        float sg[NN];
        const float* Srow = smS + (w * 16 + lm) * SSF;
#pragma unroll
        for (int n = 0; n < NN; ++n) sg[n] = Srow[se[n]] + smSB[se[n]];  // reads first
        __builtin_amdgcn_sched_barrier(0);  // keep A-strip zeroing after S gather (regions alias)
        // zero A strip cols [0,64): lane L zeroes row L>>2, bytes (L&3)*32 .. +32
        {
            uint32x4 z{0u, 0u, 0u, 0u};
            char* zb = (char*)smAsl + (L >> 2) * (ST * 2) + (L & 3) * 32;
            *(uint32x4*)zb = z;
            *(uint32x4*)(zb + 16) = z;
        }
        float mx = -1e30f;
#pragma unroll
        for (int n = 0; n < NN; ++n) { sg[n] *= SCALE; mx = fmaxf(mx, sg[n]); }
        float sum = 0.f;
#pragma unroll
        for (int n = 0; n < NN; ++n) { sg[n] = __expf(sg[n] - mx); sum += sg[n]; }
        float inv = 1.f / sum;
#pragma unroll
        for (int j = 0; j < 4; ++j) {  // dup groups write identical totals
            int u = se[g * 4 + j];
            float tot = 0.f;
#pragma unroll
            for (int n = 0; n < NN; ++n) tot += (se[n] == u) ? sg[n] : 0.f;
            smAsl[lm * ST + u] = (__bf16)(tot * inv);
        }
    }

    // ---- P5: Y = A @ KC + bcomb (B from KCT), K=64 -> global directly ----
    loadA_l(smAsl, ST, lm, lq, af, 2);
    mmB(af, smKCT, ST, lm, lq, acc, 8, 2);
#pragma unroll
    for (int nb = 0; nb < 8; ++nb) {
        float bv = bcomb[nb * 16 + lm];
#pragma unroll
        for (int r = 0; r < 4; ++r)
            Yg[(long)(w * 16 + lq * 4 + r) * DD + nb * 16 + lm] = acc[nb][r] + bv;
    }
}

extern "C" void kernel_launch(void* const* d_in, const int* in_sizes, int n_in,
                              void* d_out, int out_size, void* d_ws, size_t ws_size,
                              hipStream_t stream) {
    const float* queries = (const float*)d_in[0];
    const float* keys    = (const float*)d_in[1];
    const int*   ccc     = (const int*)d_in[2];
    const float* Wq      = (const float*)d_in[3];
    const float* bq      = (const float*)d_in[4];
    const float* Wkv     = (const float*)d_in[5];
    const float* bkv     = (const float*)d_in[6];
    const float* Wout    = (const float*)d_in[7];
    const float* bout    = (const float*)d_in[8];
    float* out = (float*)d_out;

    __bf16* Wb    = (__bf16*)d_ws;                        // M2|Wcomb|Bq bf16 = 96 KB
    float*  bcomb = (float*)((char*)d_ws + 98304);        // 128 f32

    prep<<<dim3(128), dim3(128), 0, stream>>>(Wq, Wkv, Wout, bq, bkv, bout, Wb, bcomb);

    fused<<<dim3(BPP + NPASS), dim3(256), 0, stream>>>(
        queries, keys, ccc, Wb, bcomb, out);
}